// Round 1
// baseline (671.250 us; speedup 1.0000x reference)
//
#include <hip/hip_runtime.h>
#include <math.h>

#define NN   512
#define UU   2048
#define VV   43
#define HH   512
#define KMIX 10
#define NCLS 512
#define EPSF 1e-5f
#define KA2  44      // 1 + V
#define KCAT 555     // H + V

// d_out offsets (floats), outputs concatenated in return order:
// dist (512*1*512), h2 (1*512*512), h3 (1*512*512), phi (512*2048), wt (512*43), kappa (512*10)
#define OFF_DIST  0
#define OFF_H2    262144
#define OFF_H3    524288
#define OFF_PHI   786432
#define OFF_WT    1835008
#define OFF_KAPPA 1857024

// ws offsets (floats)
#define WS_ALPHA 0
#define WS_BETA  5120
#define WS_X2    10240
#define WS_OSUM  32768   // 512*512

// ---------------------------------------------------------------------------
// K1: abk = [eh | wt_1] @ Wh1p_w^T + b ; alpha/beta -> ws, kappa -> d_out
// grid 512 blocks (one per n), 64 threads
__global__ void abk_kernel(const float* __restrict__ eh, const float* __restrict__ wt_1,
                           const float* __restrict__ Ww, const float* __restrict__ Wb,
                           const float* __restrict__ kappa_prev,
                           float* __restrict__ alpha, float* __restrict__ beta,
                           float* __restrict__ kappa_out)
{
    __shared__ float x[KCAT];
    int n = blockIdx.x, t = threadIdx.x;
    for (int i = t; i < KCAT; i += 64)
        x[i] = (i < HH) ? eh[n*HH + i] : wt_1[n*VV + (i - HH)];
    __syncthreads();
    if (t < 30) {
        const float* w = Ww + t*KCAT;
        float s = Wb[t];
        for (int i = 0; i < KCAT; ++i) s += x[i]*w[i];
        float e = expf(s);
        if (t < 10)      alpha[n*KMIX + t]        = e + EPSF;
        else if (t < 20) beta[n*KMIX + (t-10)]    = e + EPSF;
        else             kappa_out[n*KMIX + (t-20)] = kappa_prev[n*KMIX + (t-20)] + e;
    }
}

// ---------------------------------------------------------------------------
// K2: phi[n,u] = sum_k alpha*exp(-beta*(kappa-u)^2)
// grid (U/256, N), 256 threads
__global__ void phi_kernel(const float* __restrict__ alpha, const float* __restrict__ beta,
                           const float* __restrict__ kappa, float* __restrict__ phi)
{
    int n = blockIdx.y;
    int u = blockIdx.x*256 + threadIdx.x;
    __shared__ float a[KMIX], b[KMIX], kp[KMIX];
    int t = threadIdx.x;
    if (t < KMIX) { a[t] = alpha[n*KMIX+t]; b[t] = beta[n*KMIX+t]; kp[t] = kappa[n*KMIX+t]; }
    __syncthreads();
    float uu = (float)u, s = 0.f;
#pragma unroll
    for (int k = 0; k < KMIX; ++k) {
        float d = kp[k] - uu;
        s += a[k]*expf(-b[k]*d*d);
    }
    phi[(size_t)n*UU + u] = s;
}

// ---------------------------------------------------------------------------
// K3: wt[n,v] = sum_u cx[n,u,v]*phi[n,u]   (streams 180MB of cx -> HBM-bound)
// grid N blocks, 256 threads; each thread owns whole rows (contiguous 172B / lane)
__global__ void wt_kernel(const float* __restrict__ cx, const float* __restrict__ phi,
                          float* __restrict__ wt)
{
    int n = blockIdx.x, t = threadIdx.x;
    float acc[VV];
#pragma unroll
    for (int v = 0; v < VV; ++v) acc[v] = 0.f;
    const float* cxn = cx + (size_t)n*UU*VV;
    const float* phn = phi + (size_t)n*UU;
    for (int it = 0; it < UU/256; ++it) {
        int u = it*256 + t;
        float p = phn[u];
        const float* row = cxn + (size_t)u*VV;
#pragma unroll
        for (int v = 0; v < VV; ++v) acc[v] += row[v]*p;
    }
    __shared__ float red[4][VV];
    int lane = t & 63, wid = t >> 6;
#pragma unroll
    for (int v = 0; v < VV; ++v) {
        float val = acc[v];
#pragma unroll
        for (int off = 32; off > 0; off >>= 1)
            val += __shfl_down(val, off, 64);
        if (lane == 0) red[wid][v] = val;
    }
    __syncthreads();
    if (t < VV)
        wt[n*VV + t] = red[0][t] + red[1][t] + red[2][t] + red[3][t];
}

// ---------------------------------------------------------------------------
// K4: x2 = [xt | wt]  (512 x 44)
__global__ void build_x2(const float* __restrict__ xt, const float* __restrict__ wt,
                         float* __restrict__ x2)
{
    int i = blockIdx.x*256 + threadIdx.x;
    if (i >= NN*KA2) return;
    int n = i / KA2, c = i % KA2;
    x2[i] = (c == 0) ? xt[n] : wt[n*VV + (c-1)];
}

// ---------------------------------------------------------------------------
// K5/K6: fused GRU cell. C tile 16n x 64j per block, thread = 1n x 4j.
// grid (512/64, 512/16) = (8,32), 256 threads.
template<int KA, bool RELUA, bool WRITE_SUM>
__global__ void gru_kernel(const float* __restrict__ A, const float* __restrict__ Hprev,
                           const float* __restrict__ wih, const float* __restrict__ whh,
                           const float* __restrict__ bih, const float* __restrict__ bhh,
                           float* __restrict__ Hout, const float* __restrict__ Res,
                           float* __restrict__ Osum)
{
    int t  = threadIdx.x;
    int nl = t >> 4;           // 0..15
    int jg = t & 15;           // 0..15
    int n = blockIdx.y*16 + nl;
    int j = blockIdx.x*64 + jg*4;

    float accR[4] = {0.f,0.f,0.f,0.f};
    float accZ[4] = {0.f,0.f,0.f,0.f};
    float accGi[4] = {0.f,0.f,0.f,0.f};
    float accGh[4] = {0.f,0.f,0.f,0.f};

    // gi part: A (N x KA) @ wih^T rows j, j+512, j+1024
    const float* arow = A + (size_t)n*KA;
    for (int k = 0; k < KA; k += 4) {
        float4 a4 = *(const float4*)(arow + k);
        if (RELUA) {
            a4.x = fmaxf(a4.x, 0.f); a4.y = fmaxf(a4.y, 0.f);
            a4.z = fmaxf(a4.z, 0.f); a4.w = fmaxf(a4.w, 0.f);
        }
#pragma unroll
        for (int jj = 0; jj < 4; ++jj) {
            const float4 r4 = *(const float4*)(wih + (size_t)(j+jj)*KA + k);
            const float4 z4 = *(const float4*)(wih + (size_t)(j+jj+512)*KA + k);
            const float4 n4 = *(const float4*)(wih + (size_t)(j+jj+1024)*KA + k);
            accR[jj]  += a4.x*r4.x + a4.y*r4.y + a4.z*r4.z + a4.w*r4.w;
            accZ[jj]  += a4.x*z4.x + a4.y*z4.y + a4.z*z4.z + a4.w*z4.w;
            accGi[jj] += a4.x*n4.x + a4.y*n4.y + a4.z*n4.z + a4.w*n4.w;
        }
    }
    // gh part: Hprev (N x 512) @ whh^T rows j, j+512, j+1024
    const float* hrow = Hprev + (size_t)n*HH;
    for (int k = 0; k < HH; k += 4) {
        float4 h4 = *(const float4*)(hrow + k);
#pragma unroll
        for (int jj = 0; jj < 4; ++jj) {
            const float4 r4 = *(const float4*)(whh + (size_t)(j+jj)*HH + k);
            const float4 z4 = *(const float4*)(whh + (size_t)(j+jj+512)*HH + k);
            const float4 n4 = *(const float4*)(whh + (size_t)(j+jj+1024)*HH + k);
            accR[jj]  += h4.x*r4.x + h4.y*r4.y + h4.z*r4.z + h4.w*r4.w;
            accZ[jj]  += h4.x*z4.x + h4.y*z4.y + h4.z*z4.z + h4.w*z4.w;
            accGh[jj] += h4.x*n4.x + h4.y*n4.y + h4.z*n4.z + h4.w*n4.w;
        }
    }

    float4 out4, sum4;
#pragma unroll
    for (int jj = 0; jj < 4; ++jj) {
        int jc = j + jj;
        float r  = 1.f/(1.f + expf(-(accR[jj] + bih[jc] + bhh[jc])));
        float z  = 1.f/(1.f + expf(-(accZ[jj] + bih[512+jc] + bhh[512+jc])));
        float gi = accGi[jj] + bih[1024+jc];
        float gh = accGh[jj] + bhh[1024+jc];
        float nn = tanhf(gi + r*gh);
        float hp = hrow[jc];
        float ho = (1.f - z)*nn + z*hp;
        (&out4.x)[jj] = ho;
        if (WRITE_SUM) (&sum4.x)[jj] = ho + Res[(size_t)n*HH + jc];
    }
    *(float4*)(Hout + (size_t)n*HH + j) = out4;
    if (WRITE_SUM) *(float4*)(Osum + (size_t)n*HH + j) = sum4;
}

// ---------------------------------------------------------------------------
// K7: dist = relu(osum) @ Y_w^T + Y_b.  Same tiling as GRU.
__global__ void dist_kernel(const float* __restrict__ Osum, const float* __restrict__ Yw,
                            const float* __restrict__ Yb, float* __restrict__ dist)
{
    int t  = threadIdx.x;
    int nl = t >> 4, cg = t & 15;
    int n = blockIdx.y*16 + nl;
    int c = blockIdx.x*64 + cg*4;
    float acc[4] = {0.f,0.f,0.f,0.f};
    const float* arow = Osum + (size_t)n*HH;
    for (int k = 0; k < HH; k += 4) {
        float4 a4 = *(const float4*)(arow + k);
        a4.x = fmaxf(a4.x, 0.f); a4.y = fmaxf(a4.y, 0.f);
        a4.z = fmaxf(a4.z, 0.f); a4.w = fmaxf(a4.w, 0.f);
#pragma unroll
        for (int jj = 0; jj < 4; ++jj) {
            const float4 w4 = *(const float4*)(Yw + (size_t)(c+jj)*HH + k);
            acc[jj] += a4.x*w4.x + a4.y*w4.y + a4.z*w4.z + a4.w*w4.w;
        }
    }
    float4 o;
#pragma unroll
    for (int jj = 0; jj < 4; ++jj) (&o.x)[jj] = acc[jj] + Yb[c+jj];
    *(float4*)(dist + (size_t)n*NCLS + c) = o;
}

// ---------------------------------------------------------------------------
extern "C" void kernel_launch(void* const* d_in, const int* in_sizes, int n_in,
                              void* d_out, int out_size, void* d_ws, size_t ws_size,
                              hipStream_t stream)
{
    const float* xt   = (const float*)d_in[0];
    const float* cx   = (const float*)d_in[1];
    const float* eh   = (const float*)d_in[2];   // (1,N,H) -> flat (N,H)
    const float* wt_1 = (const float*)d_in[3];
    const float* h2p  = (const float*)d_in[4];
    const float* h3p  = (const float*)d_in[5];
    const float* kp   = (const float*)d_in[6];
    const float* Ww   = (const float*)d_in[7];
    const float* Wb   = (const float*)d_in[8];
    const float* w2ih = (const float*)d_in[9];
    const float* w2hh = (const float*)d_in[10];
    const float* b2ih = (const float*)d_in[11];
    const float* b2hh = (const float*)d_in[12];
    const float* w3ih = (const float*)d_in[13];
    const float* w3hh = (const float*)d_in[14];
    const float* b3ih = (const float*)d_in[15];
    const float* b3hh = (const float*)d_in[16];
    const float* Yw   = (const float*)d_in[17];
    const float* Yb   = (const float*)d_in[18];

    float* out = (float*)d_out;
    float* ws  = (float*)d_ws;

    float* dist  = out + OFF_DIST;
    float* h2o   = out + OFF_H2;
    float* h3o   = out + OFF_H3;
    float* phi   = out + OFF_PHI;
    float* wto   = out + OFF_WT;
    float* kapo  = out + OFF_KAPPA;

    float* alpha = ws + WS_ALPHA;
    float* beta  = ws + WS_BETA;
    float* x2    = ws + WS_X2;
    float* osum  = ws + WS_OSUM;

    abk_kernel<<<NN, 64, 0, stream>>>(eh, wt_1, Ww, Wb, kp, alpha, beta, kapo);
    phi_kernel<<<dim3(UU/256, NN), 256, 0, stream>>>(alpha, beta, kapo, phi);
    wt_kernel<<<NN, 256, 0, stream>>>(cx, phi, wto);
    build_x2<<<(NN*KA2 + 255)/256, 256, 0, stream>>>(xt, wto, x2);
    gru_kernel<KA2, false, false><<<dim3(8, 32), 256, 0, stream>>>(
        x2, h2p, w2ih, w2hh, b2ih, b2hh, h2o, nullptr, nullptr);
    gru_kernel<HH, true, true><<<dim3(8, 32), 256, 0, stream>>>(
        h2o, h3p, w3ih, w3hh, b3ih, b3hh, h3o, h2o, osum);
    dist_kernel<<<dim3(8, 32), 256, 0, stream>>>(osum, Yw, Yb, dist);
}

// Round 2
// 140.953 us; speedup vs baseline: 4.7622x; 4.7622x over previous
//
#include <hip/hip_runtime.h>
#include <math.h>

typedef unsigned short ushortT;
typedef __attribute__((ext_vector_type(8))) short bf16x8;
typedef __attribute__((ext_vector_type(4))) float f32x4;

#define NN   512
#define UU   2048
#define VV   43
#define HH   512
#define KMIX 10
#define NCLS 512
#define EPSF 1e-5f
#define KA2  44      // 1 + V
#define KCAT 555     // H + V
#define KP2  576     // padded K for GRU2 concat GEMM (44 + 512 -> 576)
#define KP3  1024    // GRU3 concat K (512 + 512)

// d_out offsets (floats)
#define OFF_DIST  0
#define OFF_H2    262144
#define OFF_H3    524288
#define OFF_PHI   786432
#define OFF_WT    1835008
#define OFF_KAPPA 1857024

__device__ __forceinline__ ushortT f2bf(float f) {
    unsigned int u = __builtin_bit_cast(unsigned int, f);
    u = (u + 0x7fffu + ((u >> 16) & 1u)) >> 16;
    return (ushortT)u;
}

// ---------------------------------------------------------------------------
// K1: abk = [eh | wt_1] @ Wh1p_w^T + b ; alpha/beta -> ws, kappa -> d_out
__global__ void abk_kernel(const float* __restrict__ eh, const float* __restrict__ wt_1,
                           const float* __restrict__ Ww, const float* __restrict__ Wb,
                           const float* __restrict__ kappa_prev,
                           float* __restrict__ alpha, float* __restrict__ beta,
                           float* __restrict__ kappa_out)
{
    __shared__ float x[KCAT];
    int n = blockIdx.x, t = threadIdx.x;
    for (int i = t; i < KCAT; i += 64)
        x[i] = (i < HH) ? eh[n*HH + i] : wt_1[n*VV + (i - HH)];
    __syncthreads();
    if (t < 30) {
        const float* w = Ww + t*KCAT;
        float s = Wb[t];
        for (int i = 0; i < KCAT; ++i) s += x[i]*w[i];
        float e = expf(s);
        if (t < 10)      alpha[n*KMIX + t]          = e + EPSF;
        else if (t < 20) beta[n*KMIX + (t-10)]      = e + EPSF;
        else             kappa_out[n*KMIX + (t-20)] = kappa_prev[n*KMIX + (t-20)] + e;
    }
}

// ---------------------------------------------------------------------------
// K2: phi[n,u] = sum_k alpha*exp(-beta*(kappa-u)^2)
__global__ void phi_kernel(const float* __restrict__ alpha, const float* __restrict__ beta,
                           const float* __restrict__ kappa, float* __restrict__ phi)
{
    int n = blockIdx.y;
    int u = blockIdx.x*256 + threadIdx.x;
    __shared__ float a[KMIX], b[KMIX], kp[KMIX];
    int t = threadIdx.x;
    if (t < KMIX) { a[t] = alpha[n*KMIX+t]; b[t] = beta[n*KMIX+t]; kp[t] = kappa[n*KMIX+t]; }
    __syncthreads();
    float uu = (float)u, s = 0.f;
#pragma unroll
    for (int k = 0; k < KMIX; ++k) {
        float d = kp[k] - uu;
        s += a[k]*expf(-b[k]*d*d);
    }
    phi[(size_t)n*UU + u] = s;
}

// ---------------------------------------------------------------------------
// K3: wt[n,v] = sum_u cx[n,u,v]*phi[n,u]. LDS-staged, coalesced float4 stream.
// 512 blocks x 256 threads; chunk = 256 u-rows staged per iteration.
__global__ __launch_bounds__(256) void wt_kernel(const float* __restrict__ cx,
                          const float* __restrict__ phi, float* __restrict__ wt)
{
    __shared__ float ch[256*VV];   // 44032 B
    int n = blockIdx.x, t = threadIdx.x;
    const float* cxn = cx + (size_t)n*UU*VV;
    const float* phn = phi + (size_t)n*UU;
    float acc[VV];
#pragma unroll
    for (int v = 0; v < VV; ++v) acc[v] = 0.f;

    for (int c = 0; c < UU/256; ++c) {
        const float4* src = (const float4*)(cxn + (size_t)c*256*VV);
        __syncthreads();  // previous chunk's readers done
        for (int i = t; i < (256*VV)/4; i += 256)
            ((float4*)ch)[i] = src[i];
        __syncthreads();
        float p = phn[c*256 + t];
        const float* row = ch + t*VV;   // word stride 43 -> 2-way banks, free
#pragma unroll
        for (int v = 0; v < VV; ++v) acc[v] += row[v]*p;
    }
    __syncthreads();
    int lane = t & 63, wid = t >> 6;
#pragma unroll
    for (int v = 0; v < VV; ++v) {
        float val = acc[v];
#pragma unroll
        for (int off = 32; off > 0; off >>= 1)
            val += __shfl_down(val, off, 64);
        if (lane == 0) ch[wid*VV + v] = val;
    }
    __syncthreads();
    if (t < VV)
        wt[n*VV + t] = ch[t] + ch[VV+t] + ch[2*VV+t] + ch[3*VV+t];
}

// ---------------------------------------------------------------------------
// Weight packing: Wp (2048 x Kp bf16):
//   rows [0,512):    [wih_r | whh_r | 0pad]
//   rows [512,1024): [wih_z | whh_z | 0pad]
//   rows [1024,1536):[wih_n | 0]
//   rows [1536,2048):[0 | whh_n | 0pad]
__global__ void pack_w(const float* __restrict__ wih, const float* __restrict__ whh,
                       ushortT* __restrict__ Wp, int KA, int Kp)
{
    int idx = blockIdx.x*256 + threadIdx.x;
    if (idx >= 2048*Kp) return;
    int row = idx / Kp, col = idx - row*Kp;
    float v = 0.f;
    if (row < 1024) {
        if (col < KA) v = wih[(size_t)row*KA + col];
        else if (col < KA + 512) v = whh[(size_t)row*512 + (col - KA)];
    } else if (row < 1536) {
        if (col < KA) v = wih[(size_t)row*KA + col];
    } else {
        if (col >= KA && col < KA + 512) v = whh[(size_t)(row-512)*512 + (col - KA)];
    }
    Wp[idx] = f2bf(v);
}

__global__ void pack_yw(const float* __restrict__ Yw, ushortT* __restrict__ Ywb)
{
    int idx = blockIdx.x*256 + threadIdx.x;
    if (idx < NCLS*HH) Ywb[idx] = f2bf(Yw[idx]);
}

// A2 = [xt | wt | h2p | 0pad]  (512 x 576 bf16)
__global__ void pack_a2(const float* __restrict__ xt, const float* __restrict__ wt,
                        const float* __restrict__ h2p, ushortT* __restrict__ A2)
{
    int idx = blockIdx.x*256 + threadIdx.x;
    if (idx >= NN*KP2) return;
    int n = idx / KP2, col = idx - n*KP2;
    float v = 0.f;
    if (col == 0)        v = xt[n];
    else if (col < 44)   v = wt[n*VV + col - 1];
    else if (col < 556)  v = h2p[(size_t)n*HH + col - 44];
    A2[idx] = f2bf(v);
}

// A3[:,512:1024] = bf16(h3p)
__global__ void pack_h3p(const float* __restrict__ h3p, ushortT* __restrict__ A3)
{
    int idx = blockIdx.x*256 + threadIdx.x;
    if (idx >= NN*HH) return;
    int n = idx >> 9, j = idx & 511;
    A3[(size_t)n*KP3 + 512 + j] = f2bf(h3p[idx]);
}

// ---------------------------------------------------------------------------
// bf16 MFMA GEMM: C(512 x N f32) = A(512 x K bf16) @ W(N x K bf16)^T [+ bias]
// 64x64 block tile, 4 waves 2x2, wave 32x32 (2x2 16x16x32 fragments).
// LDS tiles [64 rows][4 slots of 16B] with slot swizzle g^((row>>1)&3).
__global__ __launch_bounds__(256) void mfma_gemm(const ushortT* __restrict__ A,
        const ushortT* __restrict__ W, int K, int N,
        const float* __restrict__ bias, float* __restrict__ C)
{
    __shared__ __align__(16) ushortT lA[64*32];
    __shared__ __align__(16) ushortT lB[64*32];
    int tid  = threadIdx.x;
    int lane = tid & 63, wid = tid >> 6;
    int wm = wid >> 1, wn = wid & 1;
    int bm0 = blockIdx.y * 64, bn0 = blockIdx.x * 64;

    // staging: thread -> (row, physical slot); fetch logical k-group g = slot ^ f(row)
    int srow = tid >> 2;
    int sslot = tid & 3;
    int sg = sslot ^ ((srow >> 1) & 3);
    const ushortT* aSrc = A + (size_t)(bm0 + srow)*K + sg*8;
    const ushortT* bSrc = W + (size_t)(bn0 + srow)*K + sg*8;

    f32x4 acc[2][2];
#pragma unroll
    for (int m = 0; m < 2; ++m)
#pragma unroll
        for (int n = 0; n < 2; ++n)
            acc[m][n] = (f32x4){0.f, 0.f, 0.f, 0.f};

    // fragment read addresses (logical k-group g2 = lane>>4, swizzled)
    int fcol = lane & 15, g2 = lane >> 4;
    int arow0 = wm*32 + fcol;          // + m*16
    int brow0 = wn*32 + fcol;          // + n*16

    int nsteps = K >> 5;
    for (int s = 0; s < nsteps; ++s) {
        int kb = s << 5;
        bf16x8 av = *(const bf16x8*)(aSrc + kb);
        bf16x8 bv = *(const bf16x8*)(bSrc + kb);
        __syncthreads();
        *(bf16x8*)&lA[tid*8] = av;     // (srow*4 + sslot)*8 == tid*8
        *(bf16x8*)&lB[tid*8] = bv;
        __syncthreads();
        bf16x8 af[2], bfr[2];
#pragma unroll
        for (int m = 0; m < 2; ++m) {
            int r = arow0 + m*16;
            af[m] = *(const bf16x8*)&lA[(r*4 + (g2 ^ ((r>>1)&3)))*8];
        }
#pragma unroll
        for (int n = 0; n < 2; ++n) {
            int r = brow0 + n*16;
            bfr[n] = *(const bf16x8*)&lB[(r*4 + (g2 ^ ((r>>1)&3)))*8];
        }
#pragma unroll
        for (int m = 0; m < 2; ++m)
#pragma unroll
            for (int n = 0; n < 2; ++n)
                acc[m][n] = __builtin_amdgcn_mfma_f32_16x16x32_bf16(af[m], bfr[n], acc[m][n], 0, 0, 0);
    }

    int row4 = (lane >> 4) * 4;
#pragma unroll
    for (int m = 0; m < 2; ++m) {
#pragma unroll
        for (int n = 0; n < 2; ++n) {
            int gr = bm0 + wm*32 + m*16 + row4;
            int gc = bn0 + wn*32 + n*16 + fcol;
            float b = bias ? bias[gc] : 0.f;
#pragma unroll
            for (int r = 0; r < 4; ++r)
                C[(size_t)(gr + r)*N + gc] = acc[m][n][r] + b;
        }
    }
}

// ---------------------------------------------------------------------------
// GRU gate-combine epilogue. C is 512x2048: [r | z | n_i | n_h].
// hout = (1-z)*tanh(n_i + bih_n + r*(n_h + bhh_n)) + z*hprev
// nextA[n*nextLd + j] = bf16(relu(hout + res))   (res may be null)
__global__ void gru_epi(const float* __restrict__ C, const float* __restrict__ bih,
                        const float* __restrict__ bhh, const float* __restrict__ hprev,
                        const float* __restrict__ res, float* __restrict__ hout,
                        ushortT* __restrict__ nextA, int nextLd)
{
    int idx = blockIdx.x*256 + threadIdx.x;
    if (idx >= NN*HH) return;
    int n = idx >> 9, j = idx & 511;
    const float* c = C + (size_t)n*2048;
    float r  = 1.f/(1.f + expf(-(c[j]      + bih[j]      + bhh[j])));
    float z  = 1.f/(1.f + expf(-(c[512+j]  + bih[512+j]  + bhh[512+j])));
    float gn = c[1024+j] + bih[1024+j] + r*(c[1536+j] + bhh[1024+j]);
    float nn = tanhf(gn);
    float h  = (1.f - z)*nn + z*hprev[idx];
    hout[idx] = h;
    float s = res ? (h + res[idx]) : h;
    nextA[(size_t)n*nextLd + j] = f2bf(fmaxf(s, 0.f));
}

// ---------------------------------------------------------------------------
extern "C" void kernel_launch(void* const* d_in, const int* in_sizes, int n_in,
                              void* d_out, int out_size, void* d_ws, size_t ws_size,
                              hipStream_t stream)
{
    const float* xt   = (const float*)d_in[0];
    const float* cx   = (const float*)d_in[1];
    const float* eh   = (const float*)d_in[2];
    const float* wt_1 = (const float*)d_in[3];
    const float* h2p  = (const float*)d_in[4];
    const float* h3p  = (const float*)d_in[5];
    const float* kp   = (const float*)d_in[6];
    const float* Ww   = (const float*)d_in[7];
    const float* Wb   = (const float*)d_in[8];
    const float* w2ih = (const float*)d_in[9];
    const float* w2hh = (const float*)d_in[10];
    const float* b2ih = (const float*)d_in[11];
    const float* b2hh = (const float*)d_in[12];
    const float* w3ih = (const float*)d_in[13];
    const float* w3hh = (const float*)d_in[14];
    const float* b3ih = (const float*)d_in[15];
    const float* b3hh = (const float*)d_in[16];
    const float* Yw   = (const float*)d_in[17];
    const float* Yb   = (const float*)d_in[18];

    float* out = (float*)d_out;
    float* dist = out + OFF_DIST;
    float* h2o  = out + OFF_H2;
    float* h3o  = out + OFF_H3;
    float* phi  = out + OFF_PHI;
    float* wto  = out + OFF_WT;
    float* kapo = out + OFF_KAPPA;

    // ws bump allocation (all 16B aligned)
    char* p = (char*)d_ws;
    float* alpha = (float*)p;            p += NN*KMIX*4;
    float* beta  = (float*)p;            p += NN*KMIX*4;
    float* C     = (float*)p;            p += (size_t)NN*2048*4;   // 4 MB, reused
    ushortT* Wp2 = (ushortT*)p;          p += (size_t)2048*KP2*2;
    ushortT* Wp3 = (ushortT*)p;          p += (size_t)2048*KP3*2;
    ushortT* Ywb = (ushortT*)p;          p += (size_t)NCLS*HH*2;
    ushortT* A2  = (ushortT*)p;          p += (size_t)NN*KP2*2;
    ushortT* A3  = (ushortT*)p;          p += (size_t)NN*KP3*2;
    ushortT* Ad  = (ushortT*)p;          p += (size_t)NN*HH*2;

    // independent prep
    pack_w<<<(2048*KP2 + 255)/256, 256, 0, stream>>>(w2ih, w2hh, Wp2, KA2, KP2);
    pack_w<<<(2048*KP3 + 255)/256, 256, 0, stream>>>(w3ih, w3hh, Wp3, HH, KP3);
    pack_yw<<<(NCLS*HH + 255)/256, 256, 0, stream>>>(Yw, Ywb);
    pack_h3p<<<(NN*HH + 255)/256, 256, 0, stream>>>(h3p, A3);

    // attention window chain
    abk_kernel<<<NN, 64, 0, stream>>>(eh, wt_1, Ww, Wb, kp, alpha, beta, kapo);
    phi_kernel<<<dim3(UU/256, NN), 256, 0, stream>>>(alpha, beta, kapo, phi);
    wt_kernel<<<NN, 256, 0, stream>>>(cx, phi, wto);
    pack_a2<<<(NN*KP2 + 255)/256, 256, 0, stream>>>(xt, wto, h2p, A2);

    // GRU2
    mfma_gemm<<<dim3(2048/64, NN/64), 256, 0, stream>>>(A2, Wp2, KP2, 2048, nullptr, C);
    gru_epi<<<(NN*HH + 255)/256, 256, 0, stream>>>(C, b2ih, b2hh, h2p, nullptr, h2o, A3, KP3);

    // GRU3
    mfma_gemm<<<dim3(2048/64, NN/64), 256, 0, stream>>>(A3, Wp3, KP3, 2048, nullptr, C);
    gru_epi<<<(NN*HH + 255)/256, 256, 0, stream>>>(C, b3ih, b3hh, h3p, h2o, h3o, Ad, HH);

    // dist = relu(h3+h2) @ Yw^T + Yb
    mfma_gemm<<<dim3(NCLS/64, NN/64), 256, 0, stream>>>(Ad, Ywb, HH, NCLS, Yb, dist);
}